// Round 1
// baseline (860.920 us; speedup 1.0000x reference)
//
#include <hip/hip_runtime.h>
#include <stdint.h>

// SIMPLE k-subset sampler: log-ESP binary tree (up), forward-backward (down,
// marginals), top-down exact Gumbel sampling (must be bit-exact vs JAX threefry).
//
// PRNG variant toggle:
//   PRNG_FOLDLIKE=1 : jax_threefry_partitionable=True semantics (JAX >= 0.5
//                     default): split via counts (0,i) full pair; random_bits
//                     via 64-bit iota counter (hi,lo), bits = y0 ^ y1.
//   PRNG_FOLDLIKE=0 : legacy: split via iota(4) pairing (0,2)/(1,3); bits via
//                     pairing (i, i + S/2) -> (y0, y1).
#define PRNG_FOLDLIKE 1

#define NEGV (-10000000000.0f)

__host__ __device__ inline void tf2x32(uint32_t k0, uint32_t k1,
                                       uint32_t x0, uint32_t x1,
                                       uint32_t& y0, uint32_t& y1) {
  const uint32_t ks[3] = {k0, k1, k0 ^ k1 ^ 0x1BD11BDAu};
  x0 += ks[0]; x1 += ks[1];
  const int R0[4] = {13, 15, 26, 6};
  const int R1[4] = {17, 29, 16, 24};
#pragma unroll
  for (int i = 0; i < 5; ++i) {
    const int* R = (i & 1) ? R1 : R0;
#pragma unroll
    for (int r = 0; r < 4; ++r) {
      x0 += x1;
      x1 = (x1 << R[r]) | (x1 >> (32 - R[r]));
      x1 ^= x0;
    }
    x0 += ks[(i + 1) % 3];
    x1 += ks[(i + 2) % 3] + (uint32_t)(i + 1);
  }
  y0 = x0; y1 = x1;
}

struct TFKeys { uint32_t v[10]; };  // 5 levels x (k0,k1) sub-keys

// Gumbel draw matching jax.random.gumbel(sub, shape, f32) element f.
// f0 = flat index within sample s=0 block; half = total_size/2 = B*n*9.
__device__ inline float gumbel_val(uint32_t sk0, uint32_t sk1, int s,
                                   uint32_t f0, uint32_t half) {
  uint32_t y0, y1, bits;
#if PRNG_FOLDLIKE
  uint32_t f = (uint32_t)s * half + f0;   // 64-bit counter, hi = 0 (f < 2^32)
  tf2x32(sk0, sk1, 0u, f, y0, y1);
  bits = y0 ^ y1;
#else
  tf2x32(sk0, sk1, f0, f0 + half, y0, y1);
  bits = s ? y1 : y0;
#endif
  uint32_t fb = (bits >> 9) | 0x3f800000u;
  float u = __uint_as_float(fb) - 1.0f;             // [0,1), 23-bit grid
  const float tiny = 1.17549435e-38f;               // FLT_MIN
  float r = fmaxf(tiny, u + tiny);                  // == u*(1-tiny)+tiny in f32
  return -logf(-logf(r));
}

// log_conv single entry: out[m] = logsumexp_j ( aL[j] + (m-j>=0 ? aR[m-j] : NEG) )
// matches jax.nn.logsumexp: amax = max_j t, s = sum_j exp(t - amax) (j ascending),
// out = log(s) + amax.
__device__ inline float logconv9(const float* __restrict__ aL,
                                 const float* __restrict__ aR, int m) {
  float t[9];
#pragma unroll
  for (int j = 0; j < 9; ++j) {
    int idx = m - j;
    float rv = (idx >= 0) ? aR[idx] : NEGV;
    t[j] = aL[j] + rv;
  }
  float amax = t[0];
#pragma unroll
  for (int j = 1; j < 9; ++j) amax = fmaxf(amax, t[j]);
  float s = 0.0f;
#pragma unroll
  for (int j = 0; j < 9; ++j) s += expf(t[j] - amax);
  return logf(s) + amax;
}

__global__ __launch_bounds__(64) void simple_sampler_kernel(
    const float* __restrict__ scores, float* __restrict__ out,
    int nnodes, TFKeys keys) {
  const int b = blockIdx.x;          // flat row r = node*8 + e, B rows total
  const int tid = threadIdx.x;
  const int node = b >> 3, e = b & 7;
  const int B = nnodes * 8;
  const int out1_off = 2 * B * 32;   // samples block: 2*B*32 elements

  // levels: L0 32x9 @0, L1 16x9 @288, L2 8x9 @432, L3 4x9 @504, L4 2x9 @540,
  //         L5 1x9 @558 ; total 567
  __shared__ float lv[567];
  __shared__ float th[32];
  __shared__ float extP[288], extQ[288];
  __shared__ int cntP[64], cntQ[64];   // [2][32] counts, s*32 + i

  if (tid < 32) th[tid] = scores[node * 256 + tid * 8 + e];
  __syncthreads();

  // ---- leaf level ----
  for (int t = tid; t < 288; t += 64) {
    int i = t / 9, j = t - i * 9;
    lv[t] = (j == 0) ? 0.0f : ((j == 1) ? th[i] : NEGV);
  }
  __syncthreads();

  const int off[6] = {0, 288, 432, 504, 540, 558};

  // ---- up pass ----
  for (int lvl = 1; lvl <= 5; ++lvl) {
    int tasks = (32 >> lvl) * 9;
    for (int t = tid; t < tasks; t += 64) {
      int i = t / 9, m = t - i * 9;
      const float* aL = &lv[off[lvl - 1] + (2 * i) * 9];
      lv[off[lvl] + t] = logconv9(aL, aL + 9, m);
    }
    __syncthreads();
  }

  // ---- down pass (marginals) ----
  if (tid < 9) extP[tid] = (tid == 0) ? 0.0f : NEGV;
  __syncthreads();
  float* cur = extP;
  float* nxt = extQ;
  for (int lvl = 4; lvl >= 0; --lvl) {
    int tasks = (32 >> lvl) * 9;
    for (int t = tid; t < tasks; t += 64) {
      int no = t / 9, m = t - no * 9;
      // ext_out[2i]   = conv(ext_in[i], a[2i+1]);  ext_out[2i+1] = conv(ext_in[i], a[2i])
      const float* sib = &lv[off[lvl] + (no ^ 1) * 9];
      nxt[t] = logconv9(&cur[(no >> 1) * 9], sib, m);
    }
    __syncthreads();
    float* tmp = cur; cur = nxt; nxt = tmp;
  }

  const float logZ = lv[558 + 8];
  if (tid < 32) {
    float mval = expf(th[tid] + cur[tid * 9 + 7] - logZ);  // ext[..., k-1]
    out[out1_off + node * 256 + tid * 8 + e] = mval;
  }

  // ---- top-down sampling (2 samples) ----
  if (tid < 2) cntP[tid * 32] = 8;  // root count = k
  __syncthreads();
  int* ccur = cntP;
  int* cnxt = cntQ;
  for (int li = 0; li < 5; ++li) {
    int lvl = 4 - li;
    int npair = 16 >> lvl;                      // 1,2,4,8,16
    uint32_t half = (uint32_t)B * (uint32_t)npair * 9u;
    uint32_t sk0 = keys.v[2 * li], sk1 = keys.v[2 * li + 1];
    int tasks = 2 * npair;
    if (tid < tasks) {
      int s = tid / npair, i = tid - s * npair;
      int c = ccur[s * 32 + i];
      const float* aL = &lv[off[lvl] + (2 * i) * 9];
      const float* aR = aL + 9;
      uint32_t fbase = ((uint32_t)b * (uint32_t)npair + (uint32_t)i) * 9u;
      float best = 0.0f;
      int bj = 0;
#pragma unroll
      for (int j = 0; j < 9; ++j) {
        int idx = c - j;
        float rv = (idx >= 0) ? aR[idx] : NEGV;   // where(valid, aR[c-j], NEG)
        float g = gumbel_val(sk0, sk1, s, fbase + (uint32_t)j, half);
        float v = (aL[j] + rv) + g;               // (aL + where) + g, ref order
        if (j == 0) { best = v; }
        else if (v > best) { best = v; bj = j; }  // first-max tie-break
      }
      cnxt[s * 32 + 2 * i] = bj;
      cnxt[s * 32 + 2 * i + 1] = c - bj;
    }
    __syncthreads();
    int* tmp = ccur; ccur = cnxt; cnxt = tmp;
  }

  // ---- write samples ----
  {
    int s = tid >> 5, c = tid & 31;
    out[s * (B * 32) + node * 256 + c * 8 + e] = (float)ccur[s * 32 + c];
  }
}

extern "C" void kernel_launch(void* const* d_in, const int* in_sizes, int n_in,
                              void* d_out, int out_size, void* d_ws, size_t ws_size,
                              hipStream_t stream) {
  const float* scores = (const float*)d_in[0];
  float* out = (float*)d_out;
  const int nnodes = in_sizes[0] / (32 * 8);   // 8192
  const int B = nnodes * 8;                    // 65536 rows

  // Host-side key schedule: key = jax.random.key(42) -> data (0, 42);
  // per level: key, sub = jax.random.split(key)
  TFKeys K;
  uint32_t k0 = 0u, k1 = 42u;
  for (int t = 0; t < 5; ++t) {
    uint32_t n0, n1, s0, s1;
#if PRNG_FOLDLIKE
    tf2x32(k0, k1, 0u, 0u, n0, n1);   // new key  = tf(key, (0,0))
    tf2x32(k0, k1, 0u, 1u, s0, s1);   // sub key  = tf(key, (0,1))
#else
    uint32_t a0, a1, b0, b1;
    tf2x32(k0, k1, 0u, 2u, a0, a1);   // pair (0,2)
    tf2x32(k0, k1, 1u, 3u, b0, b1);   // pair (1,3)
    n0 = a0; n1 = b0;                 // key  = (y0(0,2), y0(1,3))
    s0 = a1; s1 = b1;                 // sub  = (y1(0,2), y1(1,3))
#endif
    K.v[2 * t] = s0; K.v[2 * t + 1] = s1;
    k0 = n0; k1 = n1;
  }

  dim3 grid((unsigned)B), block(64);
  hipLaunchKernelGGL(simple_sampler_kernel, grid, block, 0, stream,
                     scores, out, nnodes, K);
}

// Round 2
// 293.652 us; speedup vs baseline: 2.9318x; 2.9318x over previous
//
#include <hip/hip_runtime.h>
#include <stdint.h>

// Exact k-subset sampler (log-ESP tree fwd/bwd + top-down Gumbel sampling),
// support-pruned: all skipped logsumexp terms are exact-0 contributions in
// fp32 (exp(-1e10 - amax) == 0.0f), so results are bitwise identical to the
// dense reference for every value it consumes. PRNG: JAX threefry,
// jax_threefry_partitionable=True semantics (verified passing in round 1).

#define NEGV (-10000000000.0f)

__host__ __device__ inline void tf2x32(uint32_t k0, uint32_t k1,
                                       uint32_t x0, uint32_t x1,
                                       uint32_t& y0, uint32_t& y1) {
  const uint32_t ks[3] = {k0, k1, k0 ^ k1 ^ 0x1BD11BDAu};
  x0 += ks[0]; x1 += ks[1];
  const int R0[4] = {13, 15, 26, 6};
  const int R1[4] = {17, 29, 16, 24};
#pragma unroll
  for (int i = 0; i < 5; ++i) {
    const int* R = (i & 1) ? R1 : R0;
#pragma unroll
    for (int r = 0; r < 4; ++r) {
      x0 += x1;
      x1 = (x1 << R[r]) | (x1 >> (32 - R[r]));
      x1 ^= x0;
    }
    x0 += ks[(i + 1) % 3];
    x1 += ks[(i + 2) % 3] + (uint32_t)(i + 1);
  }
  y0 = x0; y1 = x1;
}

struct TFKeys { uint32_t v[10]; };  // 5 levels x (k0,k1) sub-keys

__device__ inline float gumbel_from_bits(uint32_t bits) {
  uint32_t fb = (bits >> 9) | 0x3f800000u;
  float u = __uint_as_float(fb) - 1.0f;        // [0,1)
  const float tiny = 1.17549435e-38f;          // FLT_MIN
  float r = fmaxf(tiny, u + tiny);
  return -logf(-logf(r));
}

// logsumexp_{j=jlo..jhi} aL[j] + aR[m-j]; all skipped j contribute exact 0.
// Two-pass (max, then sum ascending) matches jax.nn.logsumexp bit-for-bit.
__device__ inline float lse_conv_range(const float* __restrict__ aL,
                                       const float* __restrict__ aR,
                                       int m, int jlo, int jhi) {
  float amax = aL[jlo] + aR[m - jlo];
  for (int j = jlo + 1; j <= jhi; ++j)
    amax = fmaxf(amax, aL[j] + aR[m - j]);
  float s = 0.0f;
  for (int j = jlo; j <= jhi; ++j)
    s += expf((aL[j] + aR[m - j]) - amax);
  return logf(s) + amax;
}

__global__ __launch_bounds__(64) void simple_sampler_kernel(
    const float* __restrict__ scores, float* __restrict__ out,
    int nnodes, TFKeys keys) {
  const int b = blockIdx.x;          // flat row = node*8 + e
  const int tid = threadIdx.x;
  const int node = b >> 3, e = b & 7;
  const int B = nnodes * 8;
  const int out1_off = 2 * B * 32;

  // levels: L0 32x9 @0, L1 16x9 @288, L2 8x9 @432, L3 4x9 @504, L4 2x9 @540,
  //         L5 1x9 @558. Out-of-support entries are NEVER read (index bounds
  //         below), so no init needed.
  __shared__ float lv[567];
  __shared__ float th[32];
  __shared__ float extP[144], extQ[144];
  __shared__ float gbuf[64];
  __shared__ int cntP[64], cntQ[64];   // [2][32] counts, s*32 + i

  const int off[6] = {0, 288, 432, 504, 540, 558};
  const int Ssup[6] = {2, 3, 5, 9, 9, 9};   // table support per level

  if (tid < 32) th[tid] = scores[node * 256 + tid * 8 + e];
  if (tid < 2) cntP[tid * 32] = 8;          // sampling root counts = k
  __syncthreads();
  if (tid < 32) { lv[tid * 9] = 0.0f; lv[tid * 9 + 1] = th[tid]; }
  __syncthreads();

  // ---- up pass (support-pruned) ----
#pragma unroll
  for (int lvl = 1; lvl <= 5; ++lvl) {
    const int S_in = Ssup[lvl - 1];
    const int S_out = Ssup[lvl];
    const int outs = (32 >> lvl) * S_out;   // 48,40,36,18,9 — all <= 64
    if (tid < outs) {
      int i = tid / S_out, m = tid - i * S_out;
      const float* aL = &lv[off[lvl - 1] + 2 * i * 9];
      int jlo = max(0, m - (S_in - 1));
      int jhi = min(m, S_in - 1);
      lv[off[lvl] + i * 9 + m] = lse_conv_range(aL, aL + 9, m, jlo, jhi);
    }
    __syncthreads();
  }
  const float logZ = lv[558 + 8];

  // ---- down pass ----
  // lvl 4: ext_in support = 1 (ext0 = 0.0) => single-term logsumexp == exact
  // copy of the sibling table (0.0 + x == x).
  if (tid < 18) {
    int no = tid / 9, m = tid - no * 9;
    extP[no * 9 + m] = lv[off[4] + (no ^ 1) * 9 + m];
  }
  __syncthreads();

  float* cur = extP;
  float* nxt = extQ;
#pragma unroll
  for (int lvl = 3; lvl >= 1; --lvl) {
    const int S = Ssup[lvl];                // sibling support
    const int outs = (32 >> lvl) * 9;       // 36,72,144
    for (int t = tid; t < outs; t += 64) {
      int no = t / 9, m = t - no * 9;
      const float* aL = &cur[(no >> 1) * 9];            // ext, support 9
      const float* aR = &lv[off[lvl] + (no ^ 1) * 9];   // sibling
      int jlo = max(0, m - (S - 1));
      nxt[t] = lse_conv_range(aL, aR, m, jlo, m);
    }
    __syncthreads();
    float* tmp = cur; cur = nxt; nxt = tmp;
  }

  // lvl 0: only m = k-1 = 7 is consumed; sibling leaf support 2 => j in {6,7}.
  // Fused with the marginal epilogue (same lane produces and consumes).
  if (tid < 32) {
    int no = tid;
    const float* aL = &cur[(no >> 1) * 9];
    float t6 = aL[6] + th[no ^ 1];   // + aR[1]
    float t7 = aL[7] + 0.0f;         // + aR[0]
    float amax = fmaxf(t6, t7);
    float s = expf(t6 - amax) + expf(t7 - amax);
    float ext7 = logf(s) + amax;
    out[out1_off + node * 256 + no * 8 + e] = expf((th[no] + ext7) - logZ);
  }

  // ---- top-down sampling (2 samples), parallel Gumbel precompute ----
  int* ccur = cntP;
  int* cnxt = cntQ;
#pragma unroll
  for (int li = 0; li < 5; ++li) {
    const int lvl = 4 - li;
    const int npair = 1 << li;
    const int J = Ssup[lvl];                 // structural j-superset 0..J-1
    const int tasks = 2 * npair;
    const int draws = tasks * J;             // 18,36,40,48,64 — all <= 64
    const uint32_t half = (uint32_t)B * (uint32_t)npair * 9u;
    const uint32_t sk0 = keys.v[2 * li], sk1 = keys.v[2 * li + 1];
    if (tid < draws) {
      int task = tid / J, j = tid - task * J;
      int s = task >> li, i = task & (npair - 1);
      uint32_t f = (uint32_t)s * half +
                   ((uint32_t)b * (uint32_t)npair + (uint32_t)i) * 9u +
                   (uint32_t)j;
      uint32_t y0, y1;
      tf2x32(sk0, sk1, 0u, f, y0, y1);
      gbuf[tid] = gumbel_from_bits(y0 ^ y1);
    }
    __syncthreads();
    if (tid < tasks) {
      int s = tid >> li, i = tid & (npair - 1);
      int c = ccur[s * 32 + i];
      const float* aL = &lv[off[lvl] + 2 * i * 9];
      const float* aR = aL + 9;
      const float* g = &gbuf[tid * J];
      int jlo = max(0, c - (J - 1));
      int jhi = min(c, J - 1);
      float best = (aL[jlo] + aR[c - jlo]) + g[jlo];
      int bj = jlo;
      for (int j = jlo + 1; j <= jhi; ++j) {
        float v = (aL[j] + aR[c - j]) + g[j];
        if (v > best) { best = v; bj = j; }   // first-max tie-break (asc j)
      }
      cnxt[s * 32 + 2 * i] = bj;
      cnxt[s * 32 + 2 * i + 1] = c - bj;
    }
    __syncthreads();
    int* tmp = ccur; ccur = cnxt; cnxt = tmp;
  }

  // ---- write samples ----
  {
    int s = tid >> 5, c = tid & 31;
    out[s * (B * 32) + node * 256 + c * 8 + e] = (float)ccur[s * 32 + c];
  }
}

extern "C" void kernel_launch(void* const* d_in, const int* in_sizes, int n_in,
                              void* d_out, int out_size, void* d_ws, size_t ws_size,
                              hipStream_t stream) {
  const float* scores = (const float*)d_in[0];
  float* out = (float*)d_out;
  const int nnodes = in_sizes[0] / (32 * 8);   // 8192
  const int B = nnodes * 8;                    // 65536 rows

  // key = jax.random.key(42); per level: key, sub = split(key)
  // (partitionable threefry: new = tf(key,(0,0)), sub = tf(key,(0,1)))
  TFKeys K;
  uint32_t k0 = 0u, k1 = 42u;
  for (int t = 0; t < 5; ++t) {
    uint32_t n0, n1, s0, s1;
    tf2x32(k0, k1, 0u, 0u, n0, n1);
    tf2x32(k0, k1, 0u, 1u, s0, s1);
    K.v[2 * t] = s0; K.v[2 * t + 1] = s1;
    k0 = n0; k1 = n1;
  }

  dim3 grid((unsigned)B), block(64);
  hipLaunchKernelGGL(simple_sampler_kernel, grid, block, 0, stream,
                     scores, out, nnodes, K);
}

// Round 3
// 148.540 us; speedup vs baseline: 5.7959x; 1.9769x over previous
//
#include <hip/hip_runtime.h>
#include <stdint.h>

// Exact k-subset sampler, row-per-lane layout.
// One lane = one row (B = nnodes*8 rows, N=32 leaves, K=9).
// Log-ESP up-pass + need-set-pruned down-pass (marginals) + top-down Gumbel
// sampling with JAX threefry (partitionable semantics, verified rounds 1-2).
// All pruning removes only exact-0.0f logsumexp contributions / unused table
// entries => bitwise-identical values everywhere the reference consumes them.

#define NEGV (-10000000000.0f)

__host__ __device__ inline void tf2x32(uint32_t k0, uint32_t k1,
                                       uint32_t x0, uint32_t x1,
                                       uint32_t& y0, uint32_t& y1) {
  const uint32_t ks[3] = {k0, k1, k0 ^ k1 ^ 0x1BD11BDAu};
  x0 += ks[0]; x1 += ks[1];
  const int R0[4] = {13, 15, 26, 6};
  const int R1[4] = {17, 29, 16, 24};
#pragma unroll
  for (int i = 0; i < 5; ++i) {
    const int* R = (i & 1) ? R1 : R0;
#pragma unroll
    for (int r = 0; r < 4; ++r) {
      x0 += x1;
      x1 = (x1 << R[r]) | (x1 >> (32 - R[r]));
      x1 ^= x0;
    }
    x0 += ks[(i + 1) % 3];
    x1 += ks[(i + 2) % 3] + (uint32_t)(i + 1);
  }
  y0 = x0; y1 = x1;
}

struct TFKeys { uint32_t v[10]; };  // 5 levels x (k0,k1) sub-keys

__device__ inline float gumbel_draw(uint32_t sk0, uint32_t sk1, uint32_t f) {
  uint32_t y0, y1;
  tf2x32(sk0, sk1, 0u, f, y0, y1);
  uint32_t bits = y0 ^ y1;
  uint32_t fb = (bits >> 9) | 0x3f800000u;
  float u = __uint_as_float(fb) - 1.0f;        // [0,1)
  const float tiny = 1.17549435e-38f;          // FLT_MIN
  float r = fmaxf(tiny, u + tiny);
  return -logf(-logf(r));
}

// o[m] = logsumexp_{j=jlo..jhi} aL[j] + aR[m-j], two-pass, j-ascending sum.
template<int SIN, int SOUT>
__device__ inline void conv_level(const float (&aL)[SIN], const float (&aR)[SIN],
                                  float (&o)[SOUT]) {
#pragma unroll
  for (int m = 1; m < SOUT; ++m) {
    const int jlo = (m - (SIN - 1) > 0) ? (m - (SIN - 1)) : 0;
    const int jhi = (m < SIN - 1) ? m : (SIN - 1);
    float t[SIN];
#pragma unroll
    for (int j = 0; j < SIN; ++j)
      if (j >= jlo && j <= jhi) t[j] = aL[j] + aR[m - j];
    float amax = t[jlo];
#pragma unroll
    for (int j = 0; j < SIN; ++j)
      if (j > jlo && j <= jhi) amax = fmaxf(amax, t[j]);
    float s = 0.0f;
#pragma unroll
    for (int j = 0; j < SIN; ++j)
      if (j >= jlo && j <= jhi) s += expf(t[j] - amax);
    o[m] = logf(s) + amax;
  }
}

// eo[m] = logsumexp_{j=jlo..m} ein[j] + sib[m-j]   (sibling support SSIB)
template<int SSIB, int MLO, int MHI>
__device__ inline void ext_level(const float (&ein)[8], const float* sib,
                                 float (&eo)[8]) {
#pragma unroll
  for (int m = MLO; m <= MHI; ++m) {
    const int jlo = (m - (SSIB - 1) > 0) ? (m - (SSIB - 1)) : 0;
    float t[8];
#pragma unroll
    for (int j = 0; j < 8; ++j)
      if (j >= jlo && j <= m) t[j] = ein[j] + sib[m - j];
    float amax = t[jlo];
#pragma unroll
    for (int j = 0; j < 8; ++j)
      if (j > jlo && j <= m) amax = fmaxf(amax, t[j]);
    float s = 0.0f;
#pragma unroll
    for (int j = 0; j < 8; ++j)
      if (j >= jlo && j <= m) s += expf(t[j] - amax);
    eo[m] = logf(s) + amax;
  }
}

// Sampling middle levels (runtime pair loop, tables in LDS).
// LDS tab layout (per-lane column): L1 base 0 (w2), L2 base 32 (w4),
// L3 base 64 (w8), L4 base 96 (w8). 112 entries total.
template<int LI, int J, int BASE, int W>
__device__ inline void sample_mid(const float* tab, int* cnt, int lane,
                                  uint32_t sk0, uint32_t sk1, int s,
                                  uint32_t bu, uint32_t Bu) {
  constexpr int NPAIR = 1 << LI;
  const uint32_t half = Bu * (uint32_t)NPAIR * 9u;
#pragma unroll 1
  for (int i = NPAIR - 1; i >= 0; --i) {
    int c = cnt[i * 64 + lane];
    float aL[J], aR[J];
    aL[0] = 0.0f; aR[0] = 0.0f;
#pragma unroll
    for (int x = 1; x < J; ++x) {
      aL[x] = tab[(BASE + (2 * i) * W + x - 1) * 64 + lane];
      aR[x] = tab[(BASE + (2 * i + 1) * W + x - 1) * 64 + lane];
    }
    uint32_t fb = (uint32_t)s * half + (bu * (uint32_t)NPAIR + (uint32_t)i) * 9u;
    float best = -3.0e38f; int bj = 0;
#pragma unroll
    for (int j = 0; j < J; ++j) {
      float g = gumbel_draw(sk0, sk1, fb + (uint32_t)j);
      int idx = c - j;
      float ar = aR[0];
#pragma unroll
      for (int x = 1; x < J; ++x) ar = (idx == x) ? aR[x] : ar;
      float v = (aL[j] + ar) + g;
      if (idx >= 0 && idx <= J - 1 && v > best) { best = v; bj = j; }
    }
    cnt[(2 * i) * 64 + lane] = bj;
    cnt[(2 * i + 1) * 64 + lane] = c - bj;
  }
}

__global__ __launch_bounds__(64, 1) void simple_sampler_kernel(
    const float* __restrict__ scores, float* __restrict__ out,
    int nnodes, TFKeys keys) {
  const int lane = threadIdx.x;
  const int blk = blockIdx.x;
  const int row = blk * 64 + lane;
  const int node = row >> 3, e = row & 7;
  const int B = nnodes * 8;
  const uint32_t bu = (uint32_t)row, Bu = (uint32_t)B;

  __shared__ float tab[112 * 64];   // 28 KB tables; reused as transpose tile
  __shared__ int cnt[16 * 64];      // 4 KB sampling counts
  float* tile = tab;                // alias (tables dead before tile use)

  // ---- load theta (registers, static everywhere) ----
  float th[32];
#pragma unroll
  for (int c = 0; c < 32; ++c) th[c] = scores[node * 256 + c * 8 + e];

  // ---- up pass ----
  // L1: m=1 lse(thR,thL) [j-ascending: t0=thR, t1=thL], m=2 = thL+thR exact.
#pragma unroll
  for (int i = 0; i < 16; ++i) {
    float tL = th[2 * i], tR = th[2 * i + 1];
    float amax = fmaxf(tR, tL);
    float s = expf(tR - amax) + expf(tL - amax);
    tab[(i * 2 + 0) * 64 + lane] = logf(s) + amax;
    tab[(i * 2 + 1) * 64 + lane] = tL + tR;
  }
  // L2 (8 nodes, support 3 -> 5)
#pragma unroll 1
  for (int i = 0; i < 8; ++i) {
    float aL[3], aR[3], o[5];
    aL[0] = 0.0f; aR[0] = 0.0f;
#pragma unroll
    for (int x = 1; x < 3; ++x) {
      aL[x] = tab[((2 * i) * 2 + x - 1) * 64 + lane];
      aR[x] = tab[((2 * i + 1) * 2 + x - 1) * 64 + lane];
    }
    conv_level<3, 5>(aL, aR, o);
#pragma unroll
    for (int m = 1; m < 5; ++m) tab[(32 + i * 4 + m - 1) * 64 + lane] = o[m];
  }
  // L3 (4 nodes, support 5 -> 9)
#pragma unroll 1
  for (int i = 0; i < 4; ++i) {
    float aL[5], aR[5], o[9];
    aL[0] = 0.0f; aR[0] = 0.0f;
#pragma unroll
    for (int x = 1; x < 5; ++x) {
      aL[x] = tab[(32 + (2 * i) * 4 + x - 1) * 64 + lane];
      aR[x] = tab[(32 + (2 * i + 1) * 4 + x - 1) * 64 + lane];
    }
    conv_level<5, 9>(aL, aR, o);
#pragma unroll
    for (int m = 1; m < 9; ++m) tab[(64 + i * 8 + m - 1) * 64 + lane] = o[m];
  }
  // L4 (2 nodes, support 9 -> 9 truncated)
#pragma unroll 1
  for (int i = 0; i < 2; ++i) {
    float aL[9], aR[9], o[9];
    aL[0] = 0.0f; aR[0] = 0.0f;
#pragma unroll
    for (int x = 1; x < 9; ++x) {
      aL[x] = tab[(64 + (2 * i) * 8 + x - 1) * 64 + lane];
      aR[x] = tab[(64 + (2 * i + 1) * 8 + x - 1) * 64 + lane];
    }
    conv_level<9, 9>(aL, aR, o);
#pragma unroll
    for (int m = 1; m < 9; ++m) tab[(96 + i * 8 + m - 1) * 64 + lane] = o[m];
  }
  // logZ = root[8]
  float logZ;
  {
    float a0[9], a1[9];
    a0[0] = 0.0f; a1[0] = 0.0f;
#pragma unroll
    for (int x = 1; x < 9; ++x) {
      a0[x] = tab[(96 + x - 1) * 64 + lane];
      a1[x] = tab[(96 + 8 + x - 1) * 64 + lane];
    }
    float t[9];
#pragma unroll
    for (int j = 0; j < 9; ++j) t[j] = a0[j] + a1[8 - j];
    float amax = t[0];
#pragma unroll
    for (int j = 1; j < 9; ++j) amax = fmaxf(amax, t[j]);
    float s = 0.0f;
#pragma unroll
    for (int j = 0; j < 9; ++j) s += expf(t[j] - amax);
    logZ = logf(s) + amax;
  }

  // ---- down pass (need-set pruned), ext in registers ----
  float marg[32];
  float e4[2][8];
#pragma unroll
  for (int n = 0; n < 2; ++n) {
    e4[n][0] = 0.0f;   // root-ext conv is an exact copy of the sibling table
#pragma unroll
    for (int m = 1; m < 8; ++m)
      e4[n][m] = tab[(96 + (1 - n) * 8 + m - 1) * 64 + lane];
  }
  float e3[4][8];
#pragma unroll
  for (int n = 0; n < 4; ++n) {
    float sib[9]; sib[0] = 0.0f; sib[8] = 0.0f;
#pragma unroll
    for (int x = 1; x < 8; ++x) sib[x] = tab[(64 + (n ^ 1) * 8 + x - 1) * 64 + lane];
    ext_level<9, 0, 7>(e4[n >> 1], sib, e3[n]);
  }
  float e2[8][8];
#pragma unroll
  for (int n = 0; n < 8; ++n) {
    float sib[5]; sib[0] = 0.0f;
#pragma unroll
    for (int x = 1; x < 5; ++x) sib[x] = tab[(32 + (n ^ 1) * 4 + x - 1) * 64 + lane];
    ext_level<5, 4, 7>(e3[n >> 1], sib, e2[n]);
  }
#pragma unroll
  for (int n = 0; n < 16; ++n) {       // level-1 nodes; leaves 2n, 2n+1
    float sib[3]; sib[0] = 0.0f;
    sib[1] = tab[((n ^ 1) * 2 + 0) * 64 + lane];
    sib[2] = tab[((n ^ 1) * 2 + 1) * 64 + lane];
    float e1m[8];
    ext_level<3, 6, 7>(e2[n >> 1], sib, e1m);
    {
      float t6 = e1m[6] + th[2 * n + 1];
      float t7 = e1m[7] + 0.0f;
      float amax = fmaxf(t6, t7);
      float s = expf(t6 - amax) + expf(t7 - amax);
      float ext7 = logf(s) + amax;
      marg[2 * n] = expf((th[2 * n] + ext7) - logZ);
    }
    {
      float t6 = e1m[6] + th[2 * n];
      float t7 = e1m[7] + 0.0f;
      float amax = fmaxf(t6, t7);
      float s = expf(t6 - amax) + expf(t7 - amax);
      float ext7 = logf(s) + amax;
      marg[2 * n + 1] = expf((th[2 * n + 1] + ext7) - logZ);
    }
  }

  // ---- top-down sampling (2 samples sequentially) ----
  uint32_t mask[2];
#pragma unroll 1
  for (int s = 0; s < 2; ++s) {
    uint32_t m = 0;
    // LI=0: root, c=8 (static), L4 tables
    {
      const uint32_t half = Bu * 9u;
      float aL[9], aR[9]; aL[0] = 0.0f; aR[0] = 0.0f;
#pragma unroll
      for (int x = 1; x < 9; ++x) {
        aL[x] = tab[(96 + x - 1) * 64 + lane];
        aR[x] = tab[(96 + 8 + x - 1) * 64 + lane];
      }
      uint32_t fb = (uint32_t)s * half + bu * 9u;
      float best = -3.0e38f; int bj = 0;
#pragma unroll
      for (int j = 0; j < 9; ++j) {
        float g = gumbel_draw(keys.v[0], keys.v[1], fb + (uint32_t)j);
        float v = (aL[j] + aR[8 - j]) + g;
        if (v > best) { best = v; bj = j; }
      }
      cnt[0 * 64 + lane] = bj;
      cnt[1 * 64 + lane] = 8 - bj;
    }
    sample_mid<1, 9, 64, 8>(tab, cnt, lane, keys.v[2], keys.v[3], s, bu, Bu);
    sample_mid<2, 5, 32, 4>(tab, cnt, lane, keys.v[4], keys.v[5], s, bu, Bu);
    sample_mid<3, 3, 0, 2>(tab, cnt, lane, keys.v[6], keys.v[7], s, bu, Bu);
    // LI=4: leaves, unrolled (theta in registers), counts -> bits
    {
      const uint32_t half = Bu * 16u * 9u;
      const uint32_t sk0 = keys.v[8], sk1 = keys.v[9];
#pragma unroll
      for (int i = 15; i >= 0; --i) {
        int c = cnt[i * 64 + lane];
        uint32_t fb = (uint32_t)s * half + (bu * 16u + (uint32_t)i) * 9u;
        float aL1 = th[2 * i], aR1 = th[2 * i + 1];
        float best = -3.0e38f; int bj = 0;
        {
          float g = gumbel_draw(sk0, sk1, fb);
          float ar = (c == 0) ? 0.0f : aR1;          // aR[c], valid when c<=1
          float v = (0.0f + ar) + g;
          if (c <= 1 && v > best) { best = v; bj = 0; }
        }
        {
          float g = gumbel_draw(sk0, sk1, fb + 1u);
          int idx = c - 1;
          float ar = (idx == 0) ? 0.0f : aR1;        // aR[c-1]
          float v = (aL1 + ar) + g;
          if (idx >= 0 && idx <= 1 && v > best) { best = v; bj = 1; }
        }
        m |= ((uint32_t)bj << (2 * i)) | ((uint32_t)(c - bj) << (2 * i + 1));
      }
    }
    mask[s] = m;
  }

  // ---- coalesced output via LDS transpose tile (stride 68) ----
  const int out1_off = 2 * B * 32;
  __syncthreads();
#pragma unroll
  for (int c = 0; c < 32; ++c) tile[c * 68 + lane] = marg[c];
  __syncthreads();
  {
    float4* dst = (float4*)(out + out1_off + blk * 2048);
#pragma unroll
    for (int i2 = 0; i2 < 8; ++i2) {
      int p = i2 * 256 + lane * 4;
      int c = (p >> 3) & 31;
      int r = ((p >> 8) << 3) | (p & 7);
      dst[i2 * 64 + lane] = *(const float4*)&tile[c * 68 + r];
    }
  }
#pragma unroll 1
  for (int s = 0; s < 2; ++s) {
    __syncthreads();
#pragma unroll
    for (int c = 0; c < 32; ++c)
      tile[c * 68 + lane] = (float)((mask[s] >> c) & 1u);
    __syncthreads();
    float4* dst = (float4*)(out + s * (B * 32) + blk * 2048);
#pragma unroll
    for (int i2 = 0; i2 < 8; ++i2) {
      int p = i2 * 256 + lane * 4;
      int c = (p >> 3) & 31;
      int r = ((p >> 8) << 3) | (p & 7);
      dst[i2 * 64 + lane] = *(const float4*)&tile[c * 68 + r];
    }
  }
}

extern "C" void kernel_launch(void* const* d_in, const int* in_sizes, int n_in,
                              void* d_out, int out_size, void* d_ws, size_t ws_size,
                              hipStream_t stream) {
  const float* scores = (const float*)d_in[0];
  float* out = (float*)d_out;
  const int nnodes = in_sizes[0] / (32 * 8);   // 8192
  const int B = nnodes * 8;                    // 65536 rows

  // key = jax.random.key(42); per level: key, sub = split(key)
  // (partitionable threefry: new = tf(key,(0,0)), sub = tf(key,(0,1)))
  TFKeys K;
  uint32_t k0 = 0u, k1 = 42u;
  for (int t = 0; t < 5; ++t) {
    uint32_t n0, n1, s0, s1;
    tf2x32(k0, k1, 0u, 0u, n0, n1);
    tf2x32(k0, k1, 0u, 1u, s0, s1);
    K.v[2 * t] = s0; K.v[2 * t + 1] = s1;
    k0 = n0; k1 = n1;
  }

  dim3 grid((unsigned)(B / 64)), block(64);
  hipLaunchKernelGGL(simple_sampler_kernel, grid, block, 0, stream,
                     scores, out, nnodes, K);
}